// Round 4
// baseline (624.214 us; speedup 1.0000x reference)
//
#include <hip/hip_runtime.h>
#include <stdint.h>

typedef __attribute__((ext_vector_type(8))) short short8;
typedef __attribute__((ext_vector_type(4))) float f32x4;
typedef __attribute__((ext_vector_type(4))) unsigned short usvec4;

#define B_ 8
#define S_ 1024
#define H_ 32
#define D_ 128

static __device__ __forceinline__ unsigned short f2bf(float f) {
  uint32_t u = __builtin_bit_cast(uint32_t, f);
  u += 0x7FFFu + ((u >> 16) & 1u);
  return (unsigned short)(u >> 16);
}

// One block = 64 queries (4 waves x 16) for one (b, h). Key loop in 32-key steps.
// Inputs fp32; MFMA operands converted to bf16 (RNE). OUTPUT IS FP32.
// S^T = K*Q^T via mfma_16x16x32_bf16 (C: key=quad*4+r, q=lane&15),
// O^T += V^T*P^T, P^T B-frag built from S^T C-tiles with 8 cross-quad shuffles
// (cross-validated against an independent scalar fp32 kernel in round 3).
// K staged in LDS row-major bf16 (stride 136), V^T A-frags fragment-major (stride 520).
__global__ __launch_bounds__(256, 2)
void fa_fwd(const float* __restrict__ Qp,
            const float* __restrict__ Kp,
            const float* __restrict__ Vp,
            const float* __restrict__ BiasP,
            float* __restrict__ Op)
{
  __shared__ __align__(16) unsigned short klds[32 * 136];
  __shared__ __align__(16) unsigned short vlds[8 * 520];

  const int tid  = threadIdx.x;
  const int lane = tid & 63;
  const int w    = tid >> 6;
  const int quad = lane >> 4;
  const int c    = lane & 15;

  const int qt = blockIdx.x;
  const int h  = blockIdx.y;
  const int b  = blockIdx.z;
  const int qi = qt * 64 + w * 16 + c;

  const size_t strideS = (size_t)H_ * D_;
  const size_t bh = ((size_t)b * S_) * strideS + (size_t)h * D_;

  // Q fragments (B-operand of S^T): Q[qi][d = 32f + quad*8 + j], fp32 -> bf16
  short8 qf[4];
  {
    const float* qrow = Qp + bh + (size_t)qi * strideS;
#pragma unroll
    for (int f = 0; f < 4; ++f) {
      float4 a  = *(const float4*)(qrow + f * 32 + quad * 8);
      float4 bv = *(const float4*)(qrow + f * 32 + quad * 8 + 4);
      short8 r;
      r[0] = (short)f2bf(a.x);  r[1] = (short)f2bf(a.y);
      r[2] = (short)f2bf(a.z);  r[3] = (short)f2bf(a.w);
      r[4] = (short)f2bf(bv.x); r[5] = (short)f2bf(bv.y);
      r[6] = (short)f2bf(bv.z); r[7] = (short)f2bf(bv.w);
      qf[f] = r;
    }
  }

  const float* brow = BiasP + ((size_t)b * S_ + qi) * S_;
  const float NEGT = -1e37f;

  float m  = -INFINITY;
  float ll = 0.f;
  f32x4 acc[8];
#pragma unroll
  for (int t = 0; t < 8; ++t) acc[t] = (f32x4){0.f, 0.f, 0.f, 0.f};

  const float SL2E = 0.08838834764831845f * 1.4426950408889634f; // sm_scale * log2(e)
  const float L2E  = 1.4426950408889634f;

  for (int ks = 0; ks < S_; ks += 32) {
    // bias fragments match the S^T C layout: [q=c][k = ks + tile*16 + quad*4 + r]
    float4 b0f = *(const float4*)(brow + ks + quad * 4);
    float4 b1f = *(const float4*)(brow + ks + 16 + quad * 4);
    float b0a[4] = {b0f.x, b0f.y, b0f.z, b0f.w};
    float b1a[4] = {b1f.x, b1f.y, b1f.z, b1f.w};
    int lv = 0;
#pragma unroll
    for (int r = 0; r < 4; ++r) lv |= (b0a[r] > NEGT) | (b1a[r] > NEGT);
    const int wv = __any(lv);
    const int bvalid = __syncthreads_or(wv);
    if (!bvalid) continue;  // whole 32-key step masked for every query in block

    // Cooperative stage: K tile (row-major bf16) + V^T A-fragments (fragment-major)
    {
      const int kk = tid >> 3;   // key within step 0..31
      const int dc = tid & 7;    // d-chunk of 16

      const float* krow = Kp + bh + (size_t)(ks + kk) * strideS + dc * 16;
      unsigned short kb16[16];
#pragma unroll
      for (int i = 0; i < 4; ++i) {
        float4 kv = *(const float4*)(krow + i * 4);
        kb16[i*4+0] = f2bf(kv.x); kb16[i*4+1] = f2bf(kv.y);
        kb16[i*4+2] = f2bf(kv.z); kb16[i*4+3] = f2bf(kv.w);
      }
      usvec4* kdst = (usvec4*)(klds + kk * 136 + dc * 16);
#pragma unroll
      for (int i = 0; i < 4; ++i)
        kdst[i] = (usvec4){kb16[i*4+0], kb16[i*4+1], kb16[i*4+2], kb16[i*4+3]};

      const float* vrow = Vp + bh + (size_t)(ks + kk) * strideS + dc * 16;
      const int base = dc * 520 + (kk >> 3) * 128 + (kk & 7);
#pragma unroll
      for (int i = 0; i < 4; ++i) {
        float4 vv = *(const float4*)(vrow + i * 4);
        vlds[base + (i*4+0)*8] = f2bf(vv.x);
        vlds[base + (i*4+1)*8] = f2bf(vv.y);
        vlds[base + (i*4+2)*8] = f2bf(vv.z);
        vlds[base + (i*4+3)*8] = f2bf(vv.w);
      }
    }
    __syncthreads();

    if (wv) {
      // S^T tiles: A = K rows from LDS (key = lane&15), B = Q^T
      f32x4 st0 = (f32x4){0.f, 0.f, 0.f, 0.f};
      f32x4 st1 = (f32x4){0.f, 0.f, 0.f, 0.f};
#pragma unroll
      for (int f = 0; f < 4; ++f) {
        short8 ka = *(const short8*)(klds + c * 136 + f * 32 + quad * 8);
        short8 kb = *(const short8*)(klds + (16 + c) * 136 + f * 32 + quad * 8);
        st0 = __builtin_amdgcn_mfma_f32_16x16x32_bf16(ka, qf[f], st0, 0, 0, 0);
        st1 = __builtin_amdgcn_mfma_f32_16x16x32_bf16(kb, qf[f], st1, 0, 0, 0);
      }

      // online softmax in log2 domain; masked lanes -> -inf logits (no inf arithmetic)
      float x0[4], x1[4];
      float mt = -INFINITY;
#pragma unroll
      for (int r = 0; r < 4; ++r) {
        x0[r] = (b0a[r] > NEGT) ? fmaf(b0a[r], L2E, st0[r] * SL2E) : -INFINITY;
        x1[r] = (b1a[r] > NEGT) ? fmaf(b1a[r], L2E, st1[r] * SL2E) : -INFINITY;
        mt = fmaxf(mt, fmaxf(x0[r], x1[r]));
      }
      mt = fmaxf(mt, __shfl_xor(mt, 16));
      mt = fmaxf(mt, __shfl_xor(mt, 32));
      const float mn    = fmaxf(m, mt);
      const float alpha = exp2f(m - mn);
      m = mn;

      float p0[4], p1[4];
      float lt = 0.f;
#pragma unroll
      for (int r = 0; r < 4; ++r) {
        p0[r] = exp2f(x0[r] - mn);
        p1[r] = exp2f(x1[r] - mn);
        lt += p0[r] + p1[r];
      }
      lt += __shfl_xor(lt, 16);
      lt += __shfl_xor(lt, 32);
      ll = ll * alpha + lt;

#pragma unroll
      for (int t = 0; t < 8; ++t) {
        acc[t][0] *= alpha; acc[t][1] *= alpha;
        acc[t][2] *= alpha; acc[t][3] *= alpha;
      }

      // pack P^T C-tiles to bf16 pairs, then build PV B-fragment via cross-quad shuffles
      const int i0 = (int)(((uint32_t)f2bf(p0[0])) | ((uint32_t)f2bf(p0[1]) << 16));
      const int i1 = (int)(((uint32_t)f2bf(p0[2])) | ((uint32_t)f2bf(p0[3]) << 16));
      const int i2 = (int)(((uint32_t)f2bf(p1[0])) | ((uint32_t)f2bf(p1[1]) << 16));
      const int i3 = (int)(((uint32_t)f2bf(p1[2])) | ((uint32_t)f2bf(p1[3]) << 16));

      const int srcA = ((quad & 1) << 5) + c;  // source quad pair (same column)
      const int srcB = srcA + 16;
      const int hiT  = quad >> 1;              // which S^T tile feeds this quad

      int sA, sB, w0, w1, w2, w3;
      sA = __shfl(i0, srcA); sB = __shfl(i2, srcA); w0 = hiT ? sB : sA;
      sA = __shfl(i1, srcA); sB = __shfl(i3, srcA); w1 = hiT ? sB : sA;
      sA = __shfl(i0, srcB); sB = __shfl(i2, srcB); w2 = hiT ? sB : sA;
      sA = __shfl(i1, srcB); sB = __shfl(i3, srcB); w3 = hiT ? sB : sA;

      union { int u[4]; short8 v; } pf;
      pf.u[0] = w0; pf.u[1] = w1; pf.u[2] = w2; pf.u[3] = w3;

      // O^T[d-tile][q] accumulation: A = V^T frags from LDS (conflict-free b128)
#pragma unroll
      for (int t = 0; t < 8; ++t) {
        short8 vf = *(const short8*)(vlds + t * 520 + lane * 8);
        acc[t] = __builtin_amdgcn_mfma_f32_16x16x32_bf16(vf, pf.v, acc[t], 0, 0, 0);
      }
    }
    __syncthreads();
  }

  // epilogue: O[qi][d] = acc / l ; d = t*16 + quad*4 + r — FP32 output, 16B stores
  const float rl = 1.0f / ll;
  float* orow = Op + bh + (size_t)qi * strideS;
#pragma unroll
  for (int t = 0; t < 8; ++t) {
    float4 o;
    o.x = acc[t][0] * rl; o.y = acc[t][1] * rl;
    o.z = acc[t][2] * rl; o.w = acc[t][3] * rl;
    *(float4*)(orow + t * 16 + quad * 4) = o;
  }
}

extern "C" void kernel_launch(void* const* d_in, const int* in_sizes, int n_in,
                              void* d_out, int out_size, void* d_ws, size_t ws_size,
                              hipStream_t stream) {
  const float* q    = (const float*)d_in[0];
  const float* k    = (const float*)d_in[1];
  const float* v    = (const float*)d_in[2];
  const float* bias = (const float*)d_in[3];
  float* out = (float*)d_out;

  dim3 grid(S_ / 64, H_, B_);
  fa_fwd<<<grid, 256, 0, stream>>>(q, k, v, bias, out);
}